// Round 8
// baseline (981.583 us; speedup 1.0000x reference)
//
#include <hip/hip_runtime.h>

// 3-kernel pipeline (reverted from fusion — 8-wave per-step barrier cost
// +450cy/step vs standalone scan; baseline 550.8us beat fused 606us).
// T=1024, B=256, D=64, H=128, fp32. Z = d_ws (T*B*H fp32).
//   k_feat_mfma : z_t = tanh(x Wx^T+bx) Wih^T + (bih+bhh)   [R0 verbatim]
//   k_scan2     : h' = tanh(z_t + h Whh^T), TWO batch elems per block
//                 interleaved per step (latency hiding), 128 blocks.
//                 Per-chain ops bit-identical to R0's k_scan; hbuf padded
//                 k+(k>>4)*8 (R4-proven numerics-neutral, kills 4-way
//                 bank conflict). One lgkm-only barrier per step serves
//                 BOTH chains -> per-chain barrier count halved, chain B
//                 compute fills chain A's LDS/DPP latency.
//   k_out_mfma  : y = tanh(h Wh^T + bh) Wg^T + bg           [R0 verbatim]

#define T_SEQ 1024
#define B_SZ  256
#define D_IN  64
#define H_DIM 128

typedef __attribute__((ext_vector_type(8))) _Float16 half8;
typedef __attribute__((ext_vector_type(4))) _Float16 half4;
typedef __attribute__((ext_vector_type(4))) float f32x4;

__device__ __forceinline__ float fast_tanh(float x) {
  float ax = __builtin_fabsf(x);
  float e  = __builtin_amdgcn_exp2f(ax * -2.8853900817779268f); // -2*log2(e)
  float r  = (1.0f - e) * __builtin_amdgcn_rcpf(1.0f + e);
  return __builtin_copysignf(r, x);
}

// barrier waiting ONLY lgkmcnt (LDS): vm=63, exp=7, lgkm=0 -> imm 0xC07F
__device__ __forceinline__ void barrier_lds_only() {
  __asm__ __volatile__("" ::: "memory");
  __builtin_amdgcn_s_waitcnt(0xC07F);
  __builtin_amdgcn_s_barrier();
  __asm__ __volatile__("" ::: "memory");
}

__device__ __forceinline__ half8 pack_h8(float4 a, float4 b) {
  half8 s = { (_Float16)a.x, (_Float16)a.y, (_Float16)a.z, (_Float16)a.w,
              (_Float16)b.x, (_Float16)b.y, (_Float16)b.z, (_Float16)b.w };
  return s;
}

// 8-way lane reduction over ks=tid&7, all on VALU pipe (no DS op).
__device__ __forceinline__ float add_xor1(float x) {
  int v = __builtin_amdgcn_mov_dpp(__float_as_int(x), 0xB1, 0xF, 0xF, true);
  return x + __int_as_float(v);
}
__device__ __forceinline__ float add_xor2(float x) {
  int v = __builtin_amdgcn_mov_dpp(__float_as_int(x), 0x4E, 0xF, 0xF, true);
  return x + __int_as_float(v);
}
__device__ __forceinline__ float add_mirror8(float x) {
  int v = __builtin_amdgcn_mov_dpp(__float_as_int(x), 0x141, 0xF, 0xF, true);
  return x + __int_as_float(v);
}
__device__ __forceinline__ float dot4(float4 w, float4 h) {
  return fmaf(w.x, h.x, fmaf(w.y, h.y, fmaf(w.z, h.z, w.w * h.w)));
}

// ---------------------------------------------------------------------------
// Kernel 1 (f16 MFMA): z = tanh(x Wx^T + bx) Wih^T + (bih+bhh)  [R0 verbatim]
// ---------------------------------------------------------------------------
#define WI_S 136
#define XT_S 72
#define FM_S 136

__global__ __launch_bounds__(256) void k_feat_mfma(
    const float* __restrict__ x,  const float* __restrict__ Wx,
    const float* __restrict__ bx, const float* __restrict__ Wih,
    const float* __restrict__ bih,const float* __restrict__ bhh,
    float* __restrict__ Z)
{
  __shared__ __align__(16) _Float16 wi_l[128 * WI_S]; // 34816 B
  __shared__ __align__(16) _Float16 xt_l[64 * XT_S];  //  9216 B
  __shared__ __align__(16) _Float16 fm_l[64 * FM_S];  // 17408 B

  const int tid = threadIdx.x;
  const int l   = tid & 63;
  const int wv  = tid >> 6;
  const int ln  = l & 15;
  const int kg  = l >> 4;

  {
    const float4* w4 = (const float4*)Wih;     // 128x128 = 4096 float4
#pragma unroll
    for (int p = 0; p < 16; ++p) {
      int f = tid + p * 256;
      int row = f >> 5, kc = (f & 31) * 4;
      float4 v = w4[f];
      half4 s = { (_Float16)v.x, (_Float16)v.y, (_Float16)v.z, (_Float16)v.w };
      *(half4*)&wi_l[row * WI_S + kc] = s;
    }
  }
  half8 wxr[8][2];
#pragma unroll
  for (int nt = 0; nt < 8; ++nt)
#pragma unroll
    for (int kf = 0; kf < 2; ++kf) {
      const float* wp = Wx + (nt*16 + ln) * D_IN + kf*32 + kg*8;
      wxr[nt][kf] = pack_h8(*(const float4*)wp, *(const float4*)(wp + 4));
    }

  float bx_r[8], b2_r[8];
#pragma unroll
  for (int nt = 0; nt < 8; ++nt) {
    bx_r[nt] = bx[nt*16 + ln];
    b2_r[nt] = bih[nt*16 + ln] + bhh[nt*16 + ln];
  }

  for (int it = 0; it < 8; ++it) {
    const long tile = blockIdx.x * 8 + it;
    const long r0   = tile * 64;

    {
      const float4* x4 = (const float4*)x;
#pragma unroll
      for (int p = 0; p < 4; ++p) {
        int f = tid + p * 256;
        int row = f >> 4, kc = (f & 15) * 4;
        float4 v = x4[r0 * 16 + f];
        half4 s = { (_Float16)v.x, (_Float16)v.y, (_Float16)v.z, (_Float16)v.w };
        *(half4*)&xt_l[row * XT_S + kc] = s;
      }
    }
    barrier_lds_only();

    half8 a1[2];
#pragma unroll
    for (int kf = 0; kf < 2; ++kf)
      a1[kf] = *(const half8*)&xt_l[(wv*16 + ln) * XT_S + kf*32 + kg*8];

#pragma unroll
    for (int nt = 0; nt < 8; ++nt) {
      f32x4 acc = {0.f, 0.f, 0.f, 0.f};
#pragma unroll
      for (int kf = 0; kf < 2; ++kf)
        acc = __builtin_amdgcn_mfma_f32_16x16x32_f16(a1[kf], wxr[nt][kf], acc, 0, 0, 0);
#pragma unroll
      for (int c = 0; c < 4; ++c) {
        float v = fast_tanh(acc[c] + bx_r[nt]);
        fm_l[(wv*16 + kg*4 + c) * FM_S + nt*16 + ln] = (_Float16)v;
      }
    }

    half8 a2[4];
#pragma unroll
    for (int kf = 0; kf < 4; ++kf)
      a2[kf] = *(const half8*)&fm_l[(wv*16 + ln) * FM_S + kf*32 + kg*8];

#pragma unroll
    for (int nt = 0; nt < 8; ++nt) {
      f32x4 acc = { b2_r[nt], b2_r[nt], b2_r[nt], b2_r[nt] };
#pragma unroll
      for (int kf = 0; kf < 4; ++kf) {
        half8 bf = *(const half8*)&wi_l[(nt*16 + ln) * WI_S + kf*32 + kg*8];
        acc = __builtin_amdgcn_mfma_f32_16x16x32_f16(a2[kf], bf, acc, 0, 0, 0);
      }
#pragma unroll
      for (int c = 0; c < 4; ++c)
        Z[(r0 + wv*16 + kg*4 + c) * H_DIM + nt*16 + ln] = acc[c];
    }
    barrier_lds_only();
  }
}

// ---------------------------------------------------------------------------
// Kernel 2 (VALU scan, 2 batch elems per block interleaved): 128 blocks.
// Per-chain ops identical to R0's verified k_scan; hbuf padded (R4 fix).
// Chain B's compute fills chain A's LDS/DPP latency; one barrier per step
// serves both chains.
// ---------------------------------------------------------------------------
__global__ __launch_bounds__(256) void k_scan2(const float* __restrict__ Whh,
                                               float* __restrict__ Z)
{
  __shared__ __align__(16) float hbuf[2][2][192];   // [elem][parity][padded j]
  const int tid = threadIdx.x;
  const int b0  = blockIdx.x * 2;
  const int jg  = tid >> 3;      // 0..31
  const int ks  = tid & 7;       // 0..7
  const int k0p = ks * 24;       // padded base (k=ks*16 -> k+(k>>4)*8)

  float4 w[4][4];
#pragma unroll
  for (int r = 0; r < 4; ++r) {
    const float4* wg = (const float4*)(Whh + (jg + r*32)*H_DIM + ks*16);
#pragma unroll
    for (int m = 0; m < 4; ++m) w[r][m] = wg[m];
  }

  if (tid < 128) {
    const int jp = tid + ((tid >> 4) << 3);
    hbuf[0][0][jp] = 0.f;
    hbuf[1][0][jp] = 0.f;
  }

  const bool writer = (ks < 4);
  const int  j_out  = jg + ks*32;                    // valid for writer
  const int  j_pad  = j_out + ((j_out >> 4) << 3);
  float* zpA = Z + b0       * H_DIM + j_out;
  float* zpB = Z + (b0 + 1) * H_DIM + j_out;

  float zbA[8], zbB[8];
#pragma unroll
  for (int i = 0; i < 8; ++i) {
    zbA[i] = writer ? zpA[i * 32768] : 0.f;
    zbB[i] = writer ? zpB[i * 32768] : 0.f;
  }

  barrier_lds_only();

  for (int tb = 0; tb < T_SEQ; tb += 8) {
#pragma unroll
    for (int u = 0; u < 8; ++u) {
      const int t = tb + u;
      const float* hA = hbuf[0][t & 1];
      const float* hB = hbuf[1][t & 1];
      // issue all 8 LDS reads up front (independent; latency overlaps)
      float4 hA0 = *(const float4*)&hA[k0p];
      float4 hA1 = *(const float4*)&hA[k0p + 4];
      float4 hA2 = *(const float4*)&hA[k0p + 8];
      float4 hA3 = *(const float4*)&hA[k0p + 12];
      float4 hB0 = *(const float4*)&hB[k0p];
      float4 hB1 = *(const float4*)&hB[k0p + 4];
      float4 hB2 = *(const float4*)&hB[k0p + 8];
      float4 hB3 = *(const float4*)&hB[k0p + 12];

      float aA[4], aB[4];
#pragma unroll
      for (int r = 0; r < 4; ++r) {
        float p0 = dot4(w[r][0], hA0);
        float p1 = dot4(w[r][1], hA1);
        float p2 = dot4(w[r][2], hA2);
        float p3 = dot4(w[r][3], hA3);
        aA[r] = (p0 + p1) + (p2 + p3);
      }
#pragma unroll
      for (int r = 0; r < 4; ++r) {
        float p0 = dot4(w[r][0], hB0);
        float p1 = dot4(w[r][1], hB1);
        float p2 = dot4(w[r][2], hB2);
        float p3 = dot4(w[r][3], hB3);
        aB[r] = (p0 + p1) + (p2 + p3);
      }
#pragma unroll
      for (int r = 0; r < 4; ++r) {
        aA[r] = add_xor1(aA[r]);
        aA[r] = add_xor2(aA[r]);
        aA[r] = add_mirror8(aA[r]);
        aB[r] = add_xor1(aB[r]);
        aB[r] = add_xor2(aB[r]);
        aB[r] = add_mirror8(aB[r]);
      }
      if (writer) {
        float vA  = aA[ks] + zbA[u];
        float hnA = fast_tanh(vA);
        hbuf[0][(t & 1) ^ 1][j_pad] = hnA;
        zpA[t * 32768] = hnA;
        zbA[u] = (t + 8 < T_SEQ) ? zpA[(t + 8) * 32768] : 0.f;

        float vB  = aB[ks] + zbB[u];
        float hnB = fast_tanh(vB);
        hbuf[1][(t & 1) ^ 1][j_pad] = hnB;
        zpB[t * 32768] = hnB;
        zbB[u] = (t + 8 < T_SEQ) ? zpB[(t + 8) * 32768] : 0.f;
      }
      barrier_lds_only();
    }
  }
}

// ---------------------------------------------------------------------------
// Kernel 3 (f16 MFMA): y = tanh(h Wh^T + bh) Wg^T + bg.  [R0 verbatim]
// ---------------------------------------------------------------------------
#define TILE_R 64
#define TPW    8
#define HM_S   136
#define WH_S   136

__global__ __launch_bounds__(256) void k_out_mfma(
    const float* __restrict__ Zh, const float* __restrict__ Wh,
    const float* __restrict__ bh, const float* __restrict__ Wg,
    const float* __restrict__ bg, float* __restrict__ y)
{
  __shared__ __align__(16) _Float16 wh_l[128 * WH_S];    // 34816 B
  __shared__ __align__(16) _Float16 hm_l[TILE_R * HM_S]; // 17408 B

  const int tid = threadIdx.x;
  const int l   = tid & 63;
  const int wv  = tid >> 6;
  const int ln  = l & 15;
  const int kg  = l >> 4;

  {
    const float4* wg4 = (const float4*)Wh;
#pragma unroll
    for (int p = 0; p < 16; ++p) {
      int f = tid + p * 256;
      int row = f >> 5, kc = (f & 31) * 4;
      float4 v = wg4[f];
      half4 s = { (_Float16)v.x, (_Float16)v.y, (_Float16)v.z, (_Float16)v.w };
      *(half4*)&wh_l[row * WH_S + kc] = s;
    }
  }

  half8 wg_r[4][4];
#pragma unroll
  for (int nt2 = 0; nt2 < 4; ++nt2)
#pragma unroll
    for (int ks = 0; ks < 4; ++ks) {
      const float* wp = Wg + (nt2*16 + ln) * H_DIM + ks*32 + kg*8;
      wg_r[nt2][ks] = pack_h8(*(const float4*)wp, *(const float4*)(wp + 4));
    }

  float bh_r[8], bg_r[4];
#pragma unroll
  for (int nt = 0; nt < 8; ++nt) bh_r[nt] = bh[nt*16 + ln];
#pragma unroll
  for (int nt2 = 0; nt2 < 4; ++nt2) bg_r[nt2] = bg[nt2*16 + ln];

  for (int it = 0; it < TPW; ++it) {
    const int tile = blockIdx.x * TPW + it;
    const long r0  = (long)tile * TILE_R;
    const bool zero = (tile < 4);        // rows < 256 -> t==0 -> h = 0

    {
      const float4* hg = (const float4*)(Zh + (r0 - 256) * H_DIM);
#pragma unroll
      for (int p = 0; p < 8; ++p) {
        int f = tid + p * 256;
        int row = f >> 5, kc = (f & 31) * 4;
        float4 v;
        if (zero) { v.x = v.y = v.z = v.w = 0.f; } else { v = hg[f]; }
        half4 s = { (_Float16)v.x, (_Float16)v.y, (_Float16)v.z, (_Float16)v.w };
        *(half4*)&hm_l[row * HM_S + kc] = s;
      }
    }
    barrier_lds_only();

    half8 af[4];
#pragma unroll
    for (int ks = 0; ks < 4; ++ks)
      af[ks] = *(const half8*)&hm_l[(wv*16 + ln) * HM_S + ks*32 + kg*8];

#pragma unroll
    for (int nt = 0; nt < 8; ++nt) {
      f32x4 acc = {0.f, 0.f, 0.f, 0.f};
#pragma unroll
      for (int ks = 0; ks < 4; ++ks) {
        half8 bf = *(const half8*)&wh_l[(nt*16 + ln) * WH_S + ks*32 + kg*8];
        acc = __builtin_amdgcn_mfma_f32_16x16x32_f16(af[ks], bf, acc, 0, 0, 0);
      }
#pragma unroll
      for (int c = 0; c < 4; ++c) {
        float val = fast_tanh(acc[c] + bh_r[nt]);
        hm_l[(wv*16 + kg*4 + c) * HM_S + nt*16 + ln] = (_Float16)val;
      }
    }

    half8 a2[4];
#pragma unroll
    for (int ks = 0; ks < 4; ++ks)
      a2[ks] = *(const half8*)&hm_l[(wv*16 + ln) * HM_S + ks*32 + kg*8];

#pragma unroll
    for (int nt2 = 0; nt2 < 4; ++nt2) {
      f32x4 acc2 = { bg_r[nt2], bg_r[nt2], bg_r[nt2], bg_r[nt2] };
#pragma unroll
      for (int ks = 0; ks < 4; ++ks)
        acc2 = __builtin_amdgcn_mfma_f32_16x16x32_f16(a2[ks], wg_r[nt2][ks],
                                                      acc2, 0, 0, 0);
#pragma unroll
      for (int c = 0; c < 4; ++c)
        y[(r0 + wv*16 + kg*4 + c) * D_IN + nt2*16 + ln] = acc2[c];
    }
    barrier_lds_only();
  }
}

extern "C" void kernel_launch(void* const* d_in, const int* in_sizes, int n_in,
                              void* d_out, int out_size, void* d_ws, size_t ws_size,
                              hipStream_t stream) {
  const float* x   = (const float*)d_in[0];
  const float* Wx  = (const float*)d_in[1];
  const float* bx  = (const float*)d_in[2];
  const float* Wih = (const float*)d_in[3];
  const float* bih = (const float*)d_in[4];
  const float* Whh = (const float*)d_in[5];
  const float* bhh = (const float*)d_in[6];
  const float* Wh  = (const float*)d_in[7];
  const float* bh  = (const float*)d_in[8];
  const float* Wg  = (const float*)d_in[9];
  const float* bg  = (const float*)d_in[10];
  float* Z = (float*)d_ws;              // T*B*H*4 = 134,217,728 B
  float* y = (float*)d_out;

  k_feat_mfma<<<512, 256, 0, stream>>>(x, Wx, bx, Wih, bih, bhh, Z);
  k_scan2    <<<128, 256, 0, stream>>>(Whh, Z);
  k_out_mfma <<<512, 256, 0, stream>>>(Z, Wh, bh, Wg, bg, y);
}

// Round 9
// 556.532 us; speedup vs baseline: 1.7637x; 1.7637x over previous
//
#include <hip/hip_runtime.h>

// 3-kernel pipeline, R0-verbatim except k_scan gets (a) __launch_bounds__(256,1)
// and (b) padded hbuf. R8's counters showed VGPR_Count=72 for a kernel needing
// ~160 live (w[4][4]=64 VGPR alone) -> compiler spilled/serialized for an
// occupancy the 1-block/CU grid never uses. (256,1) lifts the VGPR cap; the
// pad (k -> k+(k>>4)*8) turns the 4-way h-read bank conflict into free 2-way.
// Per-chain numerics identical to the verified R0/R8 scan (absmax 1.953e-3).
// T=1024, B=256, D=64, H=128, fp32. Z = d_ws (T*B*H fp32).

#define T_SEQ 1024
#define B_SZ  256
#define D_IN  64
#define H_DIM 128

typedef __attribute__((ext_vector_type(8))) _Float16 half8;
typedef __attribute__((ext_vector_type(4))) _Float16 half4;
typedef __attribute__((ext_vector_type(4))) float f32x4;

__device__ __forceinline__ float fast_tanh(float x) {
  float ax = __builtin_fabsf(x);
  float e  = __builtin_amdgcn_exp2f(ax * -2.8853900817779268f); // -2*log2(e)
  float r  = (1.0f - e) * __builtin_amdgcn_rcpf(1.0f + e);
  return __builtin_copysignf(r, x);
}

// barrier waiting ONLY lgkmcnt (LDS): vm=63, exp=7, lgkm=0 -> imm 0xC07F
__device__ __forceinline__ void barrier_lds_only() {
  __asm__ __volatile__("" ::: "memory");
  __builtin_amdgcn_s_waitcnt(0xC07F);
  __builtin_amdgcn_s_barrier();
  __asm__ __volatile__("" ::: "memory");
}

__device__ __forceinline__ half8 pack_h8(float4 a, float4 b) {
  half8 s = { (_Float16)a.x, (_Float16)a.y, (_Float16)a.z, (_Float16)a.w,
              (_Float16)b.x, (_Float16)b.y, (_Float16)b.z, (_Float16)b.w };
  return s;
}

// 8-way lane reduction over ks=tid&7, all on VALU pipe (no DS op).
__device__ __forceinline__ float add_xor1(float x) {
  int v = __builtin_amdgcn_mov_dpp(__float_as_int(x), 0xB1, 0xF, 0xF, true);
  return x + __int_as_float(v);
}
__device__ __forceinline__ float add_xor2(float x) {
  int v = __builtin_amdgcn_mov_dpp(__float_as_int(x), 0x4E, 0xF, 0xF, true);
  return x + __int_as_float(v);
}
__device__ __forceinline__ float add_mirror8(float x) {
  int v = __builtin_amdgcn_mov_dpp(__float_as_int(x), 0x141, 0xF, 0xF, true);
  return x + __int_as_float(v);
}
__device__ __forceinline__ float dot4(float4 w, float4 h) {
  return fmaf(w.x, h.x, fmaf(w.y, h.y, fmaf(w.z, h.z, w.w * h.w)));
}

// ---------------------------------------------------------------------------
// Kernel 1 (f16 MFMA): z = tanh(x Wx^T + bx) Wih^T + (bih+bhh)  [R0 verbatim]
// ---------------------------------------------------------------------------
#define WI_S 136
#define XT_S 72
#define FM_S 136

__global__ __launch_bounds__(256) void k_feat_mfma(
    const float* __restrict__ x,  const float* __restrict__ Wx,
    const float* __restrict__ bx, const float* __restrict__ Wih,
    const float* __restrict__ bih,const float* __restrict__ bhh,
    float* __restrict__ Z)
{
  __shared__ __align__(16) _Float16 wi_l[128 * WI_S]; // 34816 B
  __shared__ __align__(16) _Float16 xt_l[64 * XT_S];  //  9216 B
  __shared__ __align__(16) _Float16 fm_l[64 * FM_S];  // 17408 B

  const int tid = threadIdx.x;
  const int l   = tid & 63;
  const int wv  = tid >> 6;
  const int ln  = l & 15;
  const int kg  = l >> 4;

  {
    const float4* w4 = (const float4*)Wih;     // 128x128 = 4096 float4
#pragma unroll
    for (int p = 0; p < 16; ++p) {
      int f = tid + p * 256;
      int row = f >> 5, kc = (f & 31) * 4;
      float4 v = w4[f];
      half4 s = { (_Float16)v.x, (_Float16)v.y, (_Float16)v.z, (_Float16)v.w };
      *(half4*)&wi_l[row * WI_S + kc] = s;
    }
  }
  half8 wxr[8][2];
#pragma unroll
  for (int nt = 0; nt < 8; ++nt)
#pragma unroll
    for (int kf = 0; kf < 2; ++kf) {
      const float* wp = Wx + (nt*16 + ln) * D_IN + kf*32 + kg*8;
      wxr[nt][kf] = pack_h8(*(const float4*)wp, *(const float4*)(wp + 4));
    }

  float bx_r[8], b2_r[8];
#pragma unroll
  for (int nt = 0; nt < 8; ++nt) {
    bx_r[nt] = bx[nt*16 + ln];
    b2_r[nt] = bih[nt*16 + ln] + bhh[nt*16 + ln];
  }

  for (int it = 0; it < 8; ++it) {
    const long tile = blockIdx.x * 8 + it;
    const long r0   = tile * 64;

    {
      const float4* x4 = (const float4*)x;
#pragma unroll
      for (int p = 0; p < 4; ++p) {
        int f = tid + p * 256;
        int row = f >> 4, kc = (f & 15) * 4;
        float4 v = x4[r0 * 16 + f];
        half4 s = { (_Float16)v.x, (_Float16)v.y, (_Float16)v.z, (_Float16)v.w };
        *(half4*)&xt_l[row * XT_S + kc] = s;
      }
    }
    barrier_lds_only();

    half8 a1[2];
#pragma unroll
    for (int kf = 0; kf < 2; ++kf)
      a1[kf] = *(const half8*)&xt_l[(wv*16 + ln) * XT_S + kf*32 + kg*8];

#pragma unroll
    for (int nt = 0; nt < 8; ++nt) {
      f32x4 acc = {0.f, 0.f, 0.f, 0.f};
#pragma unroll
      for (int kf = 0; kf < 2; ++kf)
        acc = __builtin_amdgcn_mfma_f32_16x16x32_f16(a1[kf], wxr[nt][kf], acc, 0, 0, 0);
#pragma unroll
      for (int c = 0; c < 4; ++c) {
        float v = fast_tanh(acc[c] + bx_r[nt]);
        fm_l[(wv*16 + kg*4 + c) * FM_S + nt*16 + ln] = (_Float16)v;
      }
    }

    half8 a2[4];
#pragma unroll
    for (int kf = 0; kf < 4; ++kf)
      a2[kf] = *(const half8*)&fm_l[(wv*16 + ln) * FM_S + kf*32 + kg*8];

#pragma unroll
    for (int nt = 0; nt < 8; ++nt) {
      f32x4 acc = { b2_r[nt], b2_r[nt], b2_r[nt], b2_r[nt] };
#pragma unroll
      for (int kf = 0; kf < 4; ++kf) {
        half8 bf = *(const half8*)&wi_l[(nt*16 + ln) * WI_S + kf*32 + kg*8];
        acc = __builtin_amdgcn_mfma_f32_16x16x32_f16(a2[kf], bf, acc, 0, 0, 0);
      }
#pragma unroll
      for (int c = 0; c < 4; ++c)
        Z[(r0 + wv*16 + kg*4 + c) * H_DIM + nt*16 + ln] = acc[c];
    }
    barrier_lds_only();
  }
}

// ---------------------------------------------------------------------------
// Kernel 2 (VALU scan, 1 WG/batch elem, 256 blocks): R0 structure with
//   (a) __launch_bounds__(256,1) -> VGPR cap lifted (R8 showed 72-VGPR
//       squeeze vs ~160 live: w[4][4]=64 spilled -> scratch traffic was
//       the hidden ~750cy/step). Grid is 1 block/CU; occupancy>4 waves/CU
//       is unreachable anyway, so the cap bought nothing.
//   (b) hbuf padded k+(k>>4)*8: 4-way -> free 2-way bank conflict.
// Per-step ops bit-identical to R0/R8 chain (passed, absmax 1.953e-3).
// ---------------------------------------------------------------------------
__global__ __launch_bounds__(256, 1) void k_scan(const float* __restrict__ Whh,
                                                 float* __restrict__ Z)
{
  __shared__ __align__(16) float hbuf[2][192];      // padded: idx k+(k>>4)*8
  const int tid = threadIdx.x;
  const int b   = blockIdx.x;
  const int jg  = tid >> 3;      // 0..31
  const int ks  = tid & 7;       // 0..7
  const int k0p = ks * 24;       // padded base (k=ks*16 -> k+(k>>4)*8)

  float4 w[4][4];
#pragma unroll
  for (int r = 0; r < 4; ++r) {
    const float4* wg = (const float4*)(Whh + (jg + r*32)*H_DIM + ks*16);
#pragma unroll
    for (int m = 0; m < 4; ++m) w[r][m] = wg[m];
  }

  if (tid < 128) hbuf[0][tid + ((tid >> 4) << 3)] = 0.f;

  const bool writer = (ks < 4);
  const int  j_out  = jg + ks*32;                 // valid for writer lanes
  const int  j_pad  = j_out + ((j_out >> 4) << 3);
  float* zp = Z + b*H_DIM + j_out;

  float zbuf[8];
#pragma unroll
  for (int i = 0; i < 8; ++i) zbuf[i] = writer ? zp[i * 32768] : 0.f;

  barrier_lds_only();

  for (int tb = 0; tb < T_SEQ; tb += 8) {
#pragma unroll
    for (int u = 0; u < 8; ++u) {
      const int t = tb + u;
      const float* h = hbuf[t & 1];
      float4 h0 = *(const float4*)&h[k0p];
      float4 h1 = *(const float4*)&h[k0p + 4];
      float4 h2 = *(const float4*)&h[k0p + 8];
      float4 h3 = *(const float4*)&h[k0p + 12];

      float a[4];
#pragma unroll
      for (int r = 0; r < 4; ++r) {
        float p0 = dot4(w[r][0], h0);
        float p1 = dot4(w[r][1], h1);
        float p2 = dot4(w[r][2], h2);
        float p3 = dot4(w[r][3], h3);
        a[r] = (p0 + p1) + (p2 + p3);
      }
#pragma unroll
      for (int r = 0; r < 4; ++r) {
        a[r] = add_xor1(a[r]);
        a[r] = add_xor2(a[r]);
        a[r] = add_mirror8(a[r]);
      }
      if (writer) {
        float v  = a[ks] + zbuf[u];
        float hn = fast_tanh(v);
        hbuf[(t & 1) ^ 1][j_pad] = hn;
        zp[t * 32768] = hn;
        zbuf[u] = (t + 8 < T_SEQ) ? zp[(t + 8) * 32768] : 0.f;
      }
      barrier_lds_only();
    }
  }
}

// ---------------------------------------------------------------------------
// Kernel 3 (f16 MFMA): y = tanh(h Wh^T + bh) Wg^T + bg.  [R0 verbatim]
// ---------------------------------------------------------------------------
#define TILE_R 64
#define TPW    8
#define HM_S   136
#define WH_S   136

__global__ __launch_bounds__(256) void k_out_mfma(
    const float* __restrict__ Zh, const float* __restrict__ Wh,
    const float* __restrict__ bh, const float* __restrict__ Wg,
    const float* __restrict__ bg, float* __restrict__ y)
{
  __shared__ __align__(16) _Float16 wh_l[128 * WH_S];    // 34816 B
  __shared__ __align__(16) _Float16 hm_l[TILE_R * HM_S]; // 17408 B

  const int tid = threadIdx.x;
  const int l   = tid & 63;
  const int wv  = tid >> 6;
  const int ln  = l & 15;
  const int kg  = l >> 4;

  {
    const float4* wg4 = (const float4*)Wh;
#pragma unroll
    for (int p = 0; p < 16; ++p) {
      int f = tid + p * 256;
      int row = f >> 5, kc = (f & 31) * 4;
      float4 v = wg4[f];
      half4 s = { (_Float16)v.x, (_Float16)v.y, (_Float16)v.z, (_Float16)v.w };
      *(half4*)&wh_l[row * WH_S + kc] = s;
    }
  }

  half8 wg_r[4][4];
#pragma unroll
  for (int nt2 = 0; nt2 < 4; ++nt2)
#pragma unroll
    for (int ks = 0; ks < 4; ++ks) {
      const float* wp = Wg + (nt2*16 + ln) * H_DIM + ks*32 + kg*8;
      wg_r[nt2][ks] = pack_h8(*(const float4*)wp, *(const float4*)(wp + 4));
    }

  float bh_r[8], bg_r[4];
#pragma unroll
  for (int nt = 0; nt < 8; ++nt) bh_r[nt] = bh[nt*16 + ln];
#pragma unroll
  for (int nt2 = 0; nt2 < 4; ++nt2) bg_r[nt2] = bg[nt2*16 + ln];

  for (int it = 0; it < TPW; ++it) {
    const int tile = blockIdx.x * TPW + it;
    const long r0  = (long)tile * TILE_R;
    const bool zero = (tile < 4);        // rows < 256 -> t==0 -> h = 0

    {
      const float4* hg = (const float4*)(Zh + (r0 - 256) * H_DIM);
#pragma unroll
      for (int p = 0; p < 8; ++p) {
        int f = tid + p * 256;
        int row = f >> 5, kc = (f & 31) * 4;
        float4 v;
        if (zero) { v.x = v.y = v.z = v.w = 0.f; } else { v = hg[f]; }
        half4 s = { (_Float16)v.x, (_Float16)v.y, (_Float16)v.z, (_Float16)v.w };
        *(half4*)&hm_l[row * HM_S + kc] = s;
      }
    }
    barrier_lds_only();

    half8 af[4];
#pragma unroll
    for (int ks = 0; ks < 4; ++ks)
      af[ks] = *(const half8*)&hm_l[(wv*16 + ln) * HM_S + ks*32 + kg*8];

#pragma unroll
    for (int nt = 0; nt < 8; ++nt) {
      f32x4 acc = {0.f, 0.f, 0.f, 0.f};
#pragma unroll
      for (int ks = 0; ks < 4; ++ks) {
        half8 bf = *(const half8*)&wh_l[(nt*16 + ln) * WH_S + ks*32 + kg*8];
        acc = __builtin_amdgcn_mfma_f32_16x16x32_f16(af[ks], bf, acc, 0, 0, 0);
      }
#pragma unroll
      for (int c = 0; c < 4; ++c) {
        float val = fast_tanh(acc[c] + bh_r[nt]);
        hm_l[(wv*16 + kg*4 + c) * HM_S + nt*16 + ln] = (_Float16)val;
      }
    }

    half8 a2[4];
#pragma unroll
    for (int ks = 0; ks < 4; ++ks)
      a2[ks] = *(const half8*)&hm_l[(wv*16 + ln) * HM_S + ks*32 + kg*8];

#pragma unroll
    for (int nt2 = 0; nt2 < 4; ++nt2) {
      f32x4 acc2 = { bg_r[nt2], bg_r[nt2], bg_r[nt2], bg_r[nt2] };
#pragma unroll
      for (int ks = 0; ks < 4; ++ks)
        acc2 = __builtin_amdgcn_mfma_f32_16x16x32_f16(a2[ks], wg_r[nt2][ks],
                                                      acc2, 0, 0, 0);
#pragma unroll
      for (int c = 0; c < 4; ++c)
        y[(r0 + wv*16 + kg*4 + c) * D_IN + nt2*16 + ln] = acc2[c];
    }
    barrier_lds_only();
  }
}

extern "C" void kernel_launch(void* const* d_in, const int* in_sizes, int n_in,
                              void* d_out, int out_size, void* d_ws, size_t ws_size,
                              hipStream_t stream) {
  const float* x   = (const float*)d_in[0];
  const float* Wx  = (const float*)d_in[1];
  const float* bx  = (const float*)d_in[2];
  const float* Wih = (const float*)d_in[3];
  const float* bih = (const float*)d_in[4];
  const float* Whh = (const float*)d_in[5];
  const float* bhh = (const float*)d_in[6];
  const float* Wh  = (const float*)d_in[7];
  const float* bh  = (const float*)d_in[8];
  const float* Wg  = (const float*)d_in[9];
  const float* bg  = (const float*)d_in[10];
  float* Z = (float*)d_ws;              // T*B*H*4 = 134,217,728 B
  float* y = (float*)d_out;

  k_feat_mfma<<<512, 256, 0, stream>>>(x, Wx, bx, Wih, bih, bhh, Z);
  k_scan     <<<B_SZ, 256, 0, stream>>>(Whh, Z);
  k_out_mfma <<<512, 256, 0, stream>>>(Z, Wh, bh, Wg, bg, y);
}

// Round 10
// 546.255 us; speedup vs baseline: 1.7969x; 1.0188x over previous
//
#include <hip/hip_runtime.h>

// 3-kernel pipeline. feat/out are R0-verbatim (verified). k_scan redesigned:
// 512 threads (8 waves, 2/SIMD): thread (j=tid>>2, ks=tid&3) computes a
// 32-wide k-slice of row j (8 dot4), quad-reduce in 2 DPP hops, writer lane
// ks==0. vs R9 (355us, 833cy/step, 4 waves = 1/SIMD): halves per-wave issue,
// adds a second wave per SIMD to hide ds_read/DPP/tanh latency, shortens the
// reduce chain 3 hops -> 2. h LDS padded jp=j+(j>>5)*24: 16-lane broadcast
// groups hit 4 distinct 4-bank spans -> conflict-free. Only the fp32 sum
// ORDER of h.Whh^T changes (perturbation ~1e-7, amplification ~10-20x ->
// negligible); f16 feat/out paths untouched, absmax stays ~1.95e-3.
// T=1024, B=256, D=64, H=128, fp32. Z = d_ws (T*B*H fp32).

#define T_SEQ 1024
#define B_SZ  256
#define D_IN  64
#define H_DIM 128

typedef __attribute__((ext_vector_type(8))) _Float16 half8;
typedef __attribute__((ext_vector_type(4))) _Float16 half4;
typedef __attribute__((ext_vector_type(4))) float f32x4;

__device__ __forceinline__ float fast_tanh(float x) {
  float ax = __builtin_fabsf(x);
  float e  = __builtin_amdgcn_exp2f(ax * -2.8853900817779268f); // -2*log2(e)
  float r  = (1.0f - e) * __builtin_amdgcn_rcpf(1.0f + e);
  return __builtin_copysignf(r, x);
}

// barrier waiting ONLY lgkmcnt (LDS): vm=63, exp=7, lgkm=0 -> imm 0xC07F
__device__ __forceinline__ void barrier_lds_only() {
  __asm__ __volatile__("" ::: "memory");
  __builtin_amdgcn_s_waitcnt(0xC07F);
  __builtin_amdgcn_s_barrier();
  __asm__ __volatile__("" ::: "memory");
}

__device__ __forceinline__ half8 pack_h8(float4 a, float4 b) {
  half8 s = { (_Float16)a.x, (_Float16)a.y, (_Float16)a.z, (_Float16)a.w,
              (_Float16)b.x, (_Float16)b.y, (_Float16)b.z, (_Float16)b.w };
  return s;
}

// quad reduction (xor1, xor2 quad_perm) — all on VALU pipe.
__device__ __forceinline__ float add_xor1(float x) {
  int v = __builtin_amdgcn_mov_dpp(__float_as_int(x), 0xB1, 0xF, 0xF, true);
  return x + __int_as_float(v);
}
__device__ __forceinline__ float add_xor2(float x) {
  int v = __builtin_amdgcn_mov_dpp(__float_as_int(x), 0x4E, 0xF, 0xF, true);
  return x + __int_as_float(v);
}
__device__ __forceinline__ float dot4(float4 w, float4 h) {
  return fmaf(w.x, h.x, fmaf(w.y, h.y, fmaf(w.z, h.z, w.w * h.w)));
}

// ---------------------------------------------------------------------------
// Kernel 1 (f16 MFMA): z = tanh(x Wx^T + bx) Wih^T + (bih+bhh)  [R0 verbatim]
// ---------------------------------------------------------------------------
#define WI_S 136
#define XT_S 72
#define FM_S 136

__global__ __launch_bounds__(256) void k_feat_mfma(
    const float* __restrict__ x,  const float* __restrict__ Wx,
    const float* __restrict__ bx, const float* __restrict__ Wih,
    const float* __restrict__ bih,const float* __restrict__ bhh,
    float* __restrict__ Z)
{
  __shared__ __align__(16) _Float16 wi_l[128 * WI_S]; // 34816 B
  __shared__ __align__(16) _Float16 xt_l[64 * XT_S];  //  9216 B
  __shared__ __align__(16) _Float16 fm_l[64 * FM_S];  // 17408 B

  const int tid = threadIdx.x;
  const int l   = tid & 63;
  const int wv  = tid >> 6;
  const int ln  = l & 15;
  const int kg  = l >> 4;

  {
    const float4* w4 = (const float4*)Wih;     // 128x128 = 4096 float4
#pragma unroll
    for (int p = 0; p < 16; ++p) {
      int f = tid + p * 256;
      int row = f >> 5, kc = (f & 31) * 4;
      float4 v = w4[f];
      half4 s = { (_Float16)v.x, (_Float16)v.y, (_Float16)v.z, (_Float16)v.w };
      *(half4*)&wi_l[row * WI_S + kc] = s;
    }
  }
  half8 wxr[8][2];
#pragma unroll
  for (int nt = 0; nt < 8; ++nt)
#pragma unroll
    for (int kf = 0; kf < 2; ++kf) {
      const float* wp = Wx + (nt*16 + ln) * D_IN + kf*32 + kg*8;
      wxr[nt][kf] = pack_h8(*(const float4*)wp, *(const float4*)(wp + 4));
    }

  float bx_r[8], b2_r[8];
#pragma unroll
  for (int nt = 0; nt < 8; ++nt) {
    bx_r[nt] = bx[nt*16 + ln];
    b2_r[nt] = bih[nt*16 + ln] + bhh[nt*16 + ln];
  }

  for (int it = 0; it < 8; ++it) {
    const long tile = blockIdx.x * 8 + it;
    const long r0   = tile * 64;

    {
      const float4* x4 = (const float4*)x;
#pragma unroll
      for (int p = 0; p < 4; ++p) {
        int f = tid + p * 256;
        int row = f >> 4, kc = (f & 15) * 4;
        float4 v = x4[r0 * 16 + f];
        half4 s = { (_Float16)v.x, (_Float16)v.y, (_Float16)v.z, (_Float16)v.w };
        *(half4*)&xt_l[row * XT_S + kc] = s;
      }
    }
    barrier_lds_only();

    half8 a1[2];
#pragma unroll
    for (int kf = 0; kf < 2; ++kf)
      a1[kf] = *(const half8*)&xt_l[(wv*16 + ln) * XT_S + kf*32 + kg*8];

#pragma unroll
    for (int nt = 0; nt < 8; ++nt) {
      f32x4 acc = {0.f, 0.f, 0.f, 0.f};
#pragma unroll
      for (int kf = 0; kf < 2; ++kf)
        acc = __builtin_amdgcn_mfma_f32_16x16x32_f16(a1[kf], wxr[nt][kf], acc, 0, 0, 0);
#pragma unroll
      for (int c = 0; c < 4; ++c) {
        float v = fast_tanh(acc[c] + bx_r[nt]);
        fm_l[(wv*16 + kg*4 + c) * FM_S + nt*16 + ln] = (_Float16)v;
      }
    }

    half8 a2[4];
#pragma unroll
    for (int kf = 0; kf < 4; ++kf)
      a2[kf] = *(const half8*)&fm_l[(wv*16 + ln) * FM_S + kf*32 + kg*8];

#pragma unroll
    for (int nt = 0; nt < 8; ++nt) {
      f32x4 acc = { b2_r[nt], b2_r[nt], b2_r[nt], b2_r[nt] };
#pragma unroll
      for (int kf = 0; kf < 4; ++kf) {
        half8 bf = *(const half8*)&wi_l[(nt*16 + ln) * WI_S + kf*32 + kg*8];
        acc = __builtin_amdgcn_mfma_f32_16x16x32_f16(a2[kf], bf, acc, 0, 0, 0);
      }
#pragma unroll
      for (int c = 0; c < 4; ++c)
        Z[(r0 + wv*16 + kg*4 + c) * H_DIM + nt*16 + ln] = acc[c];
    }
    barrier_lds_only();
  }
}

// ---------------------------------------------------------------------------
// Kernel 2 (VALU scan, 512 threads = 8 waves = 2/SIMD, 1 WG/batch elem).
// Thread (j = tid>>2, ks = tid&3): 32-wide k-slice of row j (8 dot4),
// quad-reduce (2 DPP hops), writer ks==0. hbuf padded jp = j + (j>>5)*24
// (32-float chunk at 56*ks is contiguous; 4 distinct 4-bank spans/inst).
// ---------------------------------------------------------------------------
__global__ __launch_bounds__(512, 2) void k_scan(const float* __restrict__ Whh,
                                                 float* __restrict__ Z)
{
  __shared__ __align__(16) float hbuf[2][208];      // jp = j + (j>>5)*24, max 199
  const int tid = threadIdx.x;
  const int b   = blockIdx.x;
  const int j   = tid >> 2;      // 0..127  (row)
  const int ks  = tid & 3;       // 0..3    (k-slice)
  const int k0  = ks * 32;
  const int k0p = ks * 56;       // padded base: 32ks + 24ks

  float4 w[8];
#pragma unroll
  for (int m = 0; m < 8; ++m)
    w[m] = *(const float4*)(Whh + j*H_DIM + k0 + m*4);

  if (tid < 128) hbuf[0][tid + ((tid >> 5) * 24)] = 0.f;

  const bool writer = (ks == 0);
  const int  jp     = j + ((j >> 5) * 24);
  float* zp = Z + b*H_DIM + j;

  float zbuf[8];
#pragma unroll
  for (int i = 0; i < 8; ++i) zbuf[i] = writer ? zp[i * 32768] : 0.f;

  barrier_lds_only();

  for (int tb = 0; tb < T_SEQ; tb += 8) {
#pragma unroll
    for (int u = 0; u < 8; ++u) {
      const int t = tb + u;
      const float* h = hbuf[t & 1] + k0p;
      float4 h0 = *(const float4*)(h);
      float4 h1 = *(const float4*)(h + 4);
      float4 h2 = *(const float4*)(h + 8);
      float4 h3 = *(const float4*)(h + 12);
      float4 h4 = *(const float4*)(h + 16);
      float4 h5 = *(const float4*)(h + 20);
      float4 h6 = *(const float4*)(h + 24);
      float4 h7 = *(const float4*)(h + 28);

      float p0 = dot4(w[0], h0);
      float p1 = dot4(w[1], h1);
      float p2 = dot4(w[2], h2);
      float p3 = dot4(w[3], h3);
      float p4 = dot4(w[4], h4);
      float p5 = dot4(w[5], h5);
      float p6 = dot4(w[6], h6);
      float p7 = dot4(w[7], h7);
      float a = ((p0 + p1) + (p2 + p3)) + ((p4 + p5) + (p6 + p7));

      a = add_xor1(a);       // quad lanes 0<->1, 2<->3
      a = add_xor2(a);       // quad lanes 0<->2, 1<->3

      if (writer) {
        float v  = a + zbuf[u];
        float hn = fast_tanh(v);
        hbuf[(t & 1) ^ 1][jp] = hn;
        zp[t * 32768] = hn;
        zbuf[u] = (t + 8 < T_SEQ) ? zp[(t + 8) * 32768] : 0.f;
      }
      barrier_lds_only();
    }
  }
}

// ---------------------------------------------------------------------------
// Kernel 3 (f16 MFMA): y = tanh(h Wh^T + bh) Wg^T + bg.  [R0 verbatim]
// ---------------------------------------------------------------------------
#define TILE_R 64
#define TPW    8
#define HM_S   136
#define WH_S   136

__global__ __launch_bounds__(256) void k_out_mfma(
    const float* __restrict__ Zh, const float* __restrict__ Wh,
    const float* __restrict__ bh, const float* __restrict__ Wg,
    const float* __restrict__ bg, float* __restrict__ y)
{
  __shared__ __align__(16) _Float16 wh_l[128 * WH_S];    // 34816 B
  __shared__ __align__(16) _Float16 hm_l[TILE_R * HM_S]; // 17408 B

  const int tid = threadIdx.x;
  const int l   = tid & 63;
  const int wv  = tid >> 6;
  const int ln  = l & 15;
  const int kg  = l >> 4;

  {
    const float4* wg4 = (const float4*)Wh;
#pragma unroll
    for (int p = 0; p < 16; ++p) {
      int f = tid + p * 256;
      int row = f >> 5, kc = (f & 31) * 4;
      float4 v = wg4[f];
      half4 s = { (_Float16)v.x, (_Float16)v.y, (_Float16)v.z, (_Float16)v.w };
      *(half4*)&wh_l[row * WH_S + kc] = s;
    }
  }

  half8 wg_r[4][4];
#pragma unroll
  for (int nt2 = 0; nt2 < 4; ++nt2)
#pragma unroll
    for (int ks = 0; ks < 4; ++ks) {
      const float* wp = Wg + (nt2*16 + ln) * H_DIM + ks*32 + kg*8;
      wg_r[nt2][ks] = pack_h8(*(const float4*)wp, *(const float4*)(wp + 4));
    }

  float bh_r[8], bg_r[4];
#pragma unroll
  for (int nt = 0; nt < 8; ++nt) bh_r[nt] = bh[nt*16 + ln];
#pragma unroll
  for (int nt2 = 0; nt2 < 4; ++nt2) bg_r[nt2] = bg[nt2*16 + ln];

  for (int it = 0; it < TPW; ++it) {
    const int tile = blockIdx.x * TPW + it;
    const long r0  = (long)tile * TILE_R;
    const bool zero = (tile < 4);        // rows < 256 -> t==0 -> h = 0

    {
      const float4* hg = (const float4*)(Zh + (r0 - 256) * H_DIM);
#pragma unroll
      for (int p = 0; p < 8; ++p) {
        int f = tid + p * 256;
        int row = f >> 5, kc = (f & 31) * 4;
        float4 v;
        if (zero) { v.x = v.y = v.z = v.w = 0.f; } else { v = hg[f]; }
        half4 s = { (_Float16)v.x, (_Float16)v.y, (_Float16)v.z, (_Float16)v.w };
        *(half4*)&hm_l[row * HM_S + kc] = s;
      }
    }
    barrier_lds_only();

    half8 af[4];
#pragma unroll
    for (int ks = 0; ks < 4; ++ks)
      af[ks] = *(const half8*)&hm_l[(wv*16 + ln) * HM_S + ks*32 + kg*8];

#pragma unroll
    for (int nt = 0; nt < 8; ++nt) {
      f32x4 acc = {0.f, 0.f, 0.f, 0.f};
#pragma unroll
      for (int ks = 0; ks < 4; ++ks) {
        half8 bf = *(const half8*)&wh_l[(nt*16 + ln) * WH_S + ks*32 + kg*8];
        acc = __builtin_amdgcn_mfma_f32_16x16x32_f16(af[ks], bf, acc, 0, 0, 0);
      }
#pragma unroll
      for (int c = 0; c < 4; ++c) {
        float val = fast_tanh(acc[c] + bh_r[nt]);
        hm_l[(wv*16 + kg*4 + c) * HM_S + nt*16 + ln] = (_Float16)val;
      }
    }

    half8 a2[4];
#pragma unroll
    for (int ks = 0; ks < 4; ++ks)
      a2[ks] = *(const half8*)&hm_l[(wv*16 + ln) * HM_S + ks*32 + kg*8];

#pragma unroll
    for (int nt2 = 0; nt2 < 4; ++nt2) {
      f32x4 acc2 = { bg_r[nt2], bg_r[nt2], bg_r[nt2], bg_r[nt2] };
#pragma unroll
      for (int ks = 0; ks < 4; ++ks)
        acc2 = __builtin_amdgcn_mfma_f32_16x16x32_f16(a2[ks], wg_r[nt2][ks],
                                                      acc2, 0, 0, 0);
#pragma unroll
      for (int c = 0; c < 4; ++c)
        y[(r0 + wv*16 + kg*4 + c) * D_IN + nt2*16 + ln] = acc2[c];
    }
    barrier_lds_only();
  }
}

extern "C" void kernel_launch(void* const* d_in, const int* in_sizes, int n_in,
                              void* d_out, int out_size, void* d_ws, size_t ws_size,
                              hipStream_t stream) {
  const float* x   = (const float*)d_in[0];
  const float* Wx  = (const float*)d_in[1];
  const float* bx  = (const float*)d_in[2];
  const float* Wih = (const float*)d_in[3];
  const float* bih = (const float*)d_in[4];
  const float* Whh = (const float*)d_in[5];
  const float* bhh = (const float*)d_in[6];
  const float* Wh  = (const float*)d_in[7];
  const float* bh  = (const float*)d_in[8];
  const float* Wg  = (const float*)d_in[9];
  const float* bg  = (const float*)d_in[10];
  float* Z = (float*)d_ws;              // T*B*H*4 = 134,217,728 B
  float* y = (float*)d_out;

  k_feat_mfma<<<512, 256, 0, stream>>>(x, Wx, bx, Wih, bih, bhh, Z);
  k_scan     <<<B_SZ, 512, 0, stream>>>(Whh, Z);
  k_out_mfma <<<512, 256, 0, stream>>>(Z, Wh, bh, Wg, bg, y);
}